// Round 1
// 1518.849 us; speedup vs baseline: 1.0103x; 1.0103x over previous
//
#include <hip/hip_runtime.h>
#include <cstdint>
#include <cstddef>

#define B_J0 0.1f
#define BETA 1.8f

// ---------------------------------------------------------------------------
// Phase 1: maxpool 4x4/s4 over x[64][100][2][128][128] -> xp_c[(t*64+n)*1024+p]
// ---------------------------------------------------------------------------
__global__ __launch_bounds__(256) void maxpool_kernel(
    const float* __restrict__ x, float* __restrict__ xp1, float* __restrict__ xp2)
{
    int tid = blockIdx.x * blockDim.x + threadIdx.x;   // [0, 64*100*2*1024)
    int p   = tid & 1023;
    int ntc = tid >> 10;            // (n*100+t)*2 + c
    int c   = ntc & 1;
    int nt  = ntc >> 1;             // n*100 + t
    int t   = nt % 100;
    int n   = nt / 100;
    int ph = p >> 5, pw = p & 31;
    const float* base = x + (size_t)ntc * 16384 + (size_t)(ph * 4) * 128 + pw * 4;
    float4 v0 = *(const float4*)(base);
    float m = fmaxf(fmaxf(v0.x, v0.y), fmaxf(v0.z, v0.w));
#pragma unroll
    for (int r = 1; r < 4; ++r) {
        float4 v = *(const float4*)(base + r * 128);
        m = fmaxf(m, fmaxf(fmaxf(v.x, v.y), fmaxf(v.z, v.w)));
    }
    float* dst = c ? xp2 : xp1;
    dst[(size_t)(t * 64 + n) * 1024 + p] = m;
}

// ---------------------------------------------------------------------------
// Transpose w_h2h3 (512x512, [h][k]) -> wT ([k][h]) for coalesced scan3 reads
// ---------------------------------------------------------------------------
__global__ __launch_bounds__(256) void transpose512(
    const float* __restrict__ w, float* __restrict__ wT)
{
    int tid = blockIdx.x * blockDim.x + threadIdx.x;   // k*512 + h
    int h = tid & 511, k = tid >> 9;
    wT[tid] = w[h * 512 + k];
}

// ---------------------------------------------------------------------------
// Tiled fp32 GEMM: C[r][col] = sum_k A[r][k]*B[col][k] + bias[col]
// Tile 128(M) x 64(N), BK=16, 256 threads, 8x4 microtile.
// blockIdx.z selects channel (A0/B0/bias0 vs A1/B1/bias1); writes at
// colStride*c + ntile*64 column offset, leading dim ldc.
// M=6400 (50 tiles), Nper=512 (8 tiles), K=1024. All exact multiples.
// ---------------------------------------------------------------------------
__global__ __launch_bounds__(256) void gemm_abt(
    const float* __restrict__ A0, const float* __restrict__ A1,
    const float* __restrict__ B0, const float* __restrict__ B1,
    const float* __restrict__ bias0, const float* __restrict__ bias1,
    float* __restrict__ C, int ldc, int colStride)
{
    const int K = 1024;
    int mt = blockIdx.x;
    int nt = blockIdx.y;
    int c  = blockIdx.z;
    const float* A    = c ? A1 : A0;
    const float* B    = c ? B1 : B0;
    const float* bias = c ? bias1 : bias0;

    __shared__ float As[16][128];   // [k][m]
    __shared__ float Bs[16][64];    // [k][n]

    int tid = threadIdx.x;
    int tx = tid & 15;   // n dim: 4 cols each
    int ty = tid >> 4;   // m dim: 8 rows each

    float acc[8][4] = {};
    const float* Ab = A + (size_t)mt * 128 * K;
    const float* Bb = B + (size_t)nt * 64 * K;

    for (int k0 = 0; k0 < K; k0 += 16) {
        // stage A tile: 512 float4 loads, fid = i*256 + tid (coalesced)
#pragma unroll
        for (int i = 0; i < 2; ++i) {
            int fid = i * 256 + tid;
            int k4 = fid & 3, row = fid >> 2;
            float4 v = *(const float4*)(Ab + (size_t)row * K + k0 + k4 * 4);
            As[k4 * 4 + 0][row] = v.x; As[k4 * 4 + 1][row] = v.y;
            As[k4 * 4 + 2][row] = v.z; As[k4 * 4 + 3][row] = v.w;
        }
        {
            int fid = tid;
            int k4 = fid & 3, row = fid >> 2;
            float4 v = *(const float4*)(Bb + (size_t)row * K + k0 + k4 * 4);
            Bs[k4 * 4 + 0][row] = v.x; Bs[k4 * 4 + 1][row] = v.y;
            Bs[k4 * 4 + 2][row] = v.z; Bs[k4 * 4 + 3][row] = v.w;
        }
        __syncthreads();
#pragma unroll
        for (int kk = 0; kk < 16; ++kk) {
            float a[8], b[4];
            *(float4*)&a[0] = *(const float4*)&As[kk][ty * 8];
            *(float4*)&a[4] = *(const float4*)&As[kk][ty * 8 + 4];
            *(float4*)&b[0] = *(const float4*)&Bs[kk][tx * 4];
#pragma unroll
            for (int i = 0; i < 8; ++i)
#pragma unroll
                for (int j = 0; j < 4; ++j)
                    acc[i][j] += a[i] * b[j];
        }
        __syncthreads();
    }

    int nc = nt * 64 + tx * 4;              // column within this channel's 512
    int colbase = c * colStride + nc;
    float4 bv = *(const float4*)(bias + nc);
#pragma unroll
    for (int i = 0; i < 8; ++i) {
        int row = mt * 128 + ty * 8 + i;
        float4 o;
        o.x = acc[i][0] + bv.x;
        o.y = acc[i][1] + bv.y;
        o.z = acc[i][2] + bv.z;
        o.w = acc[i][3] + bv.w;
        *(float4*)(C + (size_t)row * ldc + colbase) = o;
    }
}

// ---------------------------------------------------------------------------
// Phase 3: ALIF scan for layers 1&2 (no recurrence matmul) — one thread per
// neuron (c,n,h), serial over t. Reads in12[(t*64+n)*1024+col], writes spikes.
// ---------------------------------------------------------------------------
__global__ __launch_bounds__(256) void alif12_kernel(
    const float* __restrict__ in12, float* __restrict__ spk12,
    const float* __restrict__ tau_m1, const float* __restrict__ tau_adp1,
    const float* __restrict__ tau_m2, const float* __restrict__ tau_adp2)
{
    int tid = blockIdx.x * blockDim.x + threadIdx.x;   // [0, 65536)
    int col = tid & 1023;
    int n   = tid >> 10;
    int c = col >> 9, h = col & 511;
    float tm = c ? tau_m2[h] : tau_m1[h];
    float ta = c ? tau_adp2[h] : tau_adp1[h];
    float alpha = expf(-1.0f / tm);
    float ro    = expf(-1.0f / ta);
    float m = 0.f, s = 0.f, b = B_J0;
    for (int t = 0; t < 100; ++t) {
        size_t idx = (size_t)(t * 64 + n) * 1024 + col;
        float inp = in12[idx];
        b = ro * b + (1.f - ro) * s;
        float Bv = B_J0 + BETA * b;
        m = m * alpha + (1.f - alpha) * inp - Bv * s;
        s = (m - Bv) > 0.f ? 1.f : 0.f;
        spk12[idx] = s;
    }
}

// ---------------------------------------------------------------------------
// Phase 5: layer-3 recurrent scan. One workgroup per batch sample n (the
// recurrence is independent across n -> no grid sync). Thread h owns neuron
// (n,h). Binary spikes -> accumulate only active rows of wT (ballot-compacted
// list). Latency-optimized gather: 8 independent accumulators, 16 loads in
// flight, int4 reads of the active list. Double-buffered act[] + ballot-word
// compaction -> 2 barriers per timestep (was 3). Fused h2o projection.
// ---------------------------------------------------------------------------
__global__ __launch_bounds__(512) void scan3_kernel(
    const float* __restrict__ ff3, const float* __restrict__ wT,
    const float* __restrict__ b_h2h3,
    const float* __restrict__ tau_m3, const float* __restrict__ tau_adp3,
    const float* __restrict__ w_h2o3, const float* __restrict__ b_h2o3,
    float* __restrict__ out)
{
    __shared__ __align__(16) int act[2][512];
    __shared__ unsigned long long ballots[8];
    __shared__ float part[11 * 8];

    int n = blockIdx.x;
    int h = threadIdx.x;
    int lane = h & 63, wid = h >> 6;

    float alpha = expf(-1.0f / tau_m3[h]);
    float ro    = expf(-1.0f / tau_adp3[h]);
    float bh    = b_h2h3[h];
    const float* wcol = wT + h;

    float m = 0.f, s = 0.f, b = B_J0;
    int total = 0;   // s3(t=0 prev) == 0 -> empty active list
    int cur = 0;

    for (int t = 0; t < 100; ++t) {
        // issue ff3 load early; its latency hides under the gather
        float ff = ff3[(size_t)(t * 64 + n) * 512 + h];

        // sparse gather of active recurrent rows: 8 independent accumulator
        // chains, 16 L2 loads in flight per thread.
        const int* al = act[cur];
        float a0 = 0.f, a1 = 0.f, a2 = 0.f, a3 = 0.f;
        float a4 = 0.f, a5 = 0.f, a6 = 0.f, a7 = 0.f;
        int j = 0;
        for (; j + 15 < total; j += 16) {
            int4 k0 = *(const int4*)(al + j);
            int4 k1 = *(const int4*)(al + j + 4);
            int4 k2 = *(const int4*)(al + j + 8);
            int4 k3 = *(const int4*)(al + j + 12);
            float w0  = wcol[(size_t)k0.x * 512];
            float w1  = wcol[(size_t)k0.y * 512];
            float w2  = wcol[(size_t)k0.z * 512];
            float w3  = wcol[(size_t)k0.w * 512];
            float w4  = wcol[(size_t)k1.x * 512];
            float w5  = wcol[(size_t)k1.y * 512];
            float w6  = wcol[(size_t)k1.z * 512];
            float w7  = wcol[(size_t)k1.w * 512];
            float w8  = wcol[(size_t)k2.x * 512];
            float w9  = wcol[(size_t)k2.y * 512];
            float w10 = wcol[(size_t)k2.z * 512];
            float w11 = wcol[(size_t)k2.w * 512];
            float w12 = wcol[(size_t)k3.x * 512];
            float w13 = wcol[(size_t)k3.y * 512];
            float w14 = wcol[(size_t)k3.z * 512];
            float w15 = wcol[(size_t)k3.w * 512];
            a0 += w0;  a1 += w1;  a2 += w2;  a3 += w3;
            a4 += w4;  a5 += w5;  a6 += w6;  a7 += w7;
            a0 += w8;  a1 += w9;  a2 += w10; a3 += w11;
            a4 += w12; a5 += w13; a6 += w14; a7 += w15;
        }
        for (; j + 3 < total; j += 4) {
            int4 k = *(const int4*)(al + j);
            a0 += wcol[(size_t)k.x * 512];
            a1 += wcol[(size_t)k.y * 512];
            a2 += wcol[(size_t)k.z * 512];
            a3 += wcol[(size_t)k.w * 512];
        }
        for (; j < total; ++j) a0 += wcol[(size_t)al[j] * 512];

        float acc = (ff + bh) + (((a0 + a1) + (a2 + a3)) + ((a4 + a5) + (a6 + a7)));

        // ALIF update for neuron (n,h)
        b = ro * b + (1.f - ro) * s;
        float Bv = B_J0 + BETA * b;
        m = m * alpha + (1.f - alpha) * acc - Bv * s;
        s = (m - Bv) > 0.f ? 1.f : 0.f;

        // compaction: per-wave ballot words -> offsets; write to other buffer
        unsigned long long ball = __ballot(s > 0.f);
        if (lane == 0) ballots[wid] = ball;
        __syncthreads();                       // ballots visible
        int myoff = 0, newtotal = 0;
#pragma unroll
        for (int w = 0; w < 8; ++w) {
            int cw = __popcll(ballots[w]);
            if (w < wid) myoff += cw;
            newtotal += cw;
        }
        if (s > 0.f) {
            int lp = __popcll(ball & ((1ull << lane) - 1ull));
            act[cur ^ 1][myoff + lp] = h;      // ascending h order preserved
        }
        total = newtotal;
        cur ^= 1;
        __syncthreads();                       // act[cur] ready for next t
    }

    // fused output projection: out[n][o] = sum_h s3[h]*w_h2o3[o][h] + b[o]
#pragma unroll 1
    for (int o = 0; o < 11; ++o) {
        float v = (s > 0.f) ? w_h2o3[o * 512 + h] : 0.f;
#pragma unroll
        for (int offs = 32; offs > 0; offs >>= 1) v += __shfl_down(v, offs);
        if (lane == 0) part[o * 8 + wid] = v;
    }
    __syncthreads();
    if (h < 11) {
        float r = 0.f;
#pragma unroll
        for (int w = 0; w < 8; ++w) r += part[h * 8 + w];
        out[n * 11 + h] = r + b_h2o3[h];
    }
}

// ---------------------------------------------------------------------------
extern "C" void kernel_launch(void* const* d_in, const int* in_sizes, int n_in,
                              void* d_out, int out_size, void* d_ws, size_t ws_size,
                              hipStream_t stream)
{
    const float* x        = (const float*)d_in[0];
    const float* w_i2h1   = (const float*)d_in[1];
    const float* b_i2h1   = (const float*)d_in[2];
    const float* w_i2h2   = (const float*)d_in[3];
    const float* b_i2h2   = (const float*)d_in[4];
    const float* w_i2h3   = (const float*)d_in[5];
    const float* b_i2h3   = (const float*)d_in[6];
    const float* w_h2h3   = (const float*)d_in[7];
    const float* b_h2h3   = (const float*)d_in[8];
    const float* w_h2o3   = (const float*)d_in[9];
    const float* b_h2o3   = (const float*)d_in[10];
    const float* tau_adp1 = (const float*)d_in[11];
    const float* tau_adp2 = (const float*)d_in[12];
    const float* tau_adp3 = (const float*)d_in[13];
    const float* tau_m1   = (const float*)d_in[14];
    const float* tau_m2   = (const float*)d_in[15];
    const float* tau_m3   = (const float*)d_in[16];
    float* out = (float*)d_out;
    float* ws  = (float*)d_ws;

    // workspace layout (floats); spk12 reuses xp1, ff3 reuses xp2.
    float* xp1   = ws;                     // 6553600
    float* xp2   = ws + 6553600;           // 6553600
    float* in12  = ws + 13107200;          // 6553600
    float* wT    = ws + 19660800;          // 262144  (total ~79.7 MB)
    float* spk12 = xp1;
    float* ff3   = xp2;

    // 1) maxpool: 800 MB read (HBM-bound)
    maxpool_kernel<<<dim3(51200), dim3(256), 0, stream>>>(x, xp1, xp2);
    // 2) transpose recurrent weight (tiny)
    transpose512<<<dim3(1024), dim3(256), 0, stream>>>(w_h2h3, wT);
    // 3) in1/in2 = xp_c @ w_i2h_c^T + b_c  (both channels, one launch)
    gemm_abt<<<dim3(50, 8, 2), dim3(256), 0, stream>>>(
        xp1, xp2, w_i2h1, w_i2h2, b_i2h1, b_i2h2, in12, 1024, 512);
    // 4) layers 1&2 ALIF scan -> spikes for all timesteps
    alif12_kernel<<<dim3(256), dim3(256), 0, stream>>>(
        in12, spk12, tau_m1, tau_adp1, tau_m2, tau_adp2);
    // 5) ff3 = [s1,s2] @ w_i2h3^T + b_i2h3 over all timesteps
    gemm_abt<<<dim3(50, 8, 1), dim3(256), 0, stream>>>(
        spk12, nullptr, w_i2h3, nullptr, b_i2h3, nullptr, ff3, 512, 0);
    // 6) layer-3 recurrent scan + fused output projection
    scan3_kernel<<<dim3(64), dim3(512), 0, stream>>>(
        ff3, wT, b_h2h3, tau_m3, tau_adp3, w_h2o3, b_h2o3, out);
}